// Round 11
// baseline (115.279 us; speedup 1.0000x reference)
//
#include <hip/hip_runtime.h>

#define B_      2048
#define SYN     128
#define SEM     256
#define IN_DIM  647
#define K1      704      // 647 padded to 22*32
#define HIDDEN  1024
#define OUT_N   10000
#define NNZ     8

typedef __bf16 bf16x8 __attribute__((ext_vector_type(8)));
typedef float  f32x4  __attribute__((ext_vector_type(4)));
typedef unsigned int u32x2 __attribute__((ext_vector_type(2)));
typedef __attribute__((address_space(3))) const unsigned short* lds_cp;

__device__ __forceinline__ unsigned short f2b(float v) {
    __bf16 b = (__bf16)v;
    return __builtin_bit_cast(unsigned short, b);
}

// --------------------- prep_light: cvt_w1 + build_x only --------------------
#define NB_W1 2816   // HIDDEN*K1/256
#define NB_W2 5000   // OUT_N*HIDDEN/8/256
__global__ __launch_bounds__(256) void prep_light(
    const float* __restrict__ W1,  unsigned short* __restrict__ W1b,
    const float* __restrict__ d_onehot,
    const int*   __restrict__ cat_ix,
    const int*   __restrict__ hvb_ix,
    const int*   __restrict__ hvf_ix,
    const float* __restrict__ hvb_top,
    const float* __restrict__ hvf_top,
    const float* __restrict__ cat_embeds,
    const float* __restrict__ hvec_embeds,
    unsigned short* __restrict__ xb)
{
    const int bb = blockIdx.x, t = threadIdx.x;
    if (bb < NB_W1) {
        int idx = bb * 256 + t;
        int r = idx / K1, c = idx - r * K1;
        W1b[idx] = f2b(c < IN_DIM ? W1[r * IN_DIM + c] : 0.f);
        return;
    }
    const int b = bb - NB_W1;
    unsigned short* xrow = xb + (size_t)b * K1;
    if (t < SYN) {
        int c = cat_ix[b];
        xrow[t] = f2b(cat_embeds[(size_t)c * SYN + t]);
    }
    {
        int ix[NNZ];
        #pragma unroll
        for (int j = 0; j < NNZ; ++j) ix[j] = hvb_ix[b * NNZ + j];
        float s = hvb_top[(size_t)b * SEM + t];
        #pragma unroll
        for (int j = 0; j < NNZ; ++j) {
            bool dup = false;
            for (int k2 = 0; k2 < j; ++k2) dup = dup || (ix[j] == ix[k2]);
            if (!dup) s += hvec_embeds[(size_t)ix[j] * SEM + t];
        }
        xrow[SYN + t] = f2b(s);
    }
    {
        int ix[NNZ];
        #pragma unroll
        for (int j = 0; j < NNZ; ++j) ix[j] = hvf_ix[b * NNZ + j];
        float s = hvf_top[(size_t)b * SEM + t];
        #pragma unroll
        for (int j = 0; j < NNZ; ++j) {
            bool dup = false;
            for (int k2 = 0; k2 < j; ++k2) dup = dup || (ix[j] == ix[k2]);
            if (!dup) s += hvec_embeds[(size_t)ix[j] * SEM + t];
        }
        xrow[SYN + SEM + t] = f2b(s);
    }
    if (t < 7)       xrow[640 + t] = f2b(d_onehot[b * 7 + t]);
    else if (t < 64) xrow[640 + t] = 0;
}

// ------------------- mid: GEMM1 only (R5-exact pipeline, NI=2) --------------
__global__ __launch_bounds__(256) void mid(
    const unsigned short* __restrict__ A,    // xb
    const unsigned short* __restrict__ Bm,   // W1b
    const float* __restrict__ bias,          // b1
    unsigned short* __restrict__ H)          // hB
{
    constexpr int NI = 2, nt = K1 / 32, K = K1, ncols = HIDDEN, nbm1 = HIDDEN - 1;
    __shared__ __align__(16) unsigned short lds_a[4][128 * 32];
    __shared__ __align__(16) unsigned short lds_b[4][64 * 32];

    const int tid = threadIdx.x;
    const int wv = tid >> 6, ln = tid & 63;
    const int wr = wv >> 1, wc = wv & 1;
    const int lr = ln & 15, lh = ln >> 4;

    const int vbid = blockIdx.x;
    const int nw  = (vbid & 7) * 32 + (vbid >> 3);
    const int mt  = nw % 16, ntile = nw / 16;
    const int m0  = mt * 128, n0 = ntile * 64;

    const unsigned short* srcA[2];
    const unsigned short* srcB0;
    #pragma unroll
    for (int i = 0; i < 2; ++i) {
        int c = tid + i * 256;
        int row = c >> 2, colL = (((c & 3) ^ ((c >> 3) & 3)) << 3);
        srcA[i] = A + (size_t)(m0 + row) * K + colL;
    }
    {
        int c = tid;
        int row = c >> 2, colL = (((c & 3) ^ ((c >> 3) & 3)) << 3);
        int gr = n0 + row; if (gr > nbm1) gr = nbm1;
        srcB0 = Bm + (size_t)gr * K + colL;
    }

    auto stage = [&](int buf, int kt) {
        #pragma unroll
        for (int i = 0; i < 2; ++i)
            __builtin_amdgcn_global_load_lds(
                (__attribute__((address_space(1))) const void*)(srcA[i] + kt),
                (__attribute__((address_space(3))) void*)&lds_a[buf][(tid + i * 256) * 8], 16, 0, 0);
        __builtin_amdgcn_global_load_lds(
            (__attribute__((address_space(1))) const void*)(srcB0 + kt),
            (__attribute__((address_space(3))) void*)&lds_b[buf][tid * 8], 16, 0, 0);
    };

    int a_off[4], b_off[NI];
    #pragma unroll
    for (int mi = 0; mi < 4; ++mi) {
        int row = wr * 64 + mi * 16 + lr;
        a_off[mi] = (row * 64 + lh * 16) ^ (((row >> 1) & 3) << 4);
    }
    #pragma unroll
    for (int ni = 0; ni < NI; ++ni) {
        int row = wc * 32 + ni * 16 + lr;
        b_off[ni] = (row * 64 + lh * 16) ^ (((row >> 1) & 3) << 4);
    }

    f32x4 acc[4][NI];
    {
        f32x4 z = {0.f, 0.f, 0.f, 0.f};
        #pragma unroll
        for (int i = 0; i < 4; ++i)
            #pragma unroll
            for (int j = 0; j < NI; ++j) acc[i][j] = z;
    }

    auto frag_read = [&](bf16x8 (&af)[4], bf16x8 (&bfv)[NI], int buf) {
        lds_cp pa = (lds_cp)&lds_a[buf][0];
        lds_cp pb = (lds_cp)&lds_b[buf][0];
        #pragma unroll
        for (int mi = 0; mi < 4; ++mi) {
            unsigned ad = (unsigned)(unsigned long long)pa + a_off[mi];
            asm volatile("ds_read_b128 %0, %1" : "=v"(af[mi]) : "v"(ad));
        }
        #pragma unroll
        for (int ni = 0; ni < NI; ++ni) {
            unsigned ad = (unsigned)(unsigned long long)pb + b_off[ni];
            asm volatile("ds_read_b128 %0, %1" : "=v"(bfv[ni]) : "v"(ad));
        }
    };
    auto do_mfma = [&](bf16x8 (&af)[4], bf16x8 (&bfv)[NI]) {
        #pragma unroll
        for (int mi = 0; mi < 4; ++mi)
            #pragma unroll
            for (int ni = 0; ni < NI; ++ni)
                acc[mi][ni] = __builtin_amdgcn_mfma_f32_16x16x32_bf16(af[mi], bfv[ni], acc[mi][ni], 0, 0, 0);
    };
    auto do_part = [&](bf16x8 (&rA)[4], bf16x8 (&rB)[NI],
                       bf16x8 (&mA)[4], bf16x8 (&mB)[NI], int p) {
        frag_read(rA, rB, (p + 1) & 3);
        int tp = p + 3; if (tp > nt - 1) tp = nt - 1;
        stage((p + 3) & 3, tp * 32);
        asm volatile("s_waitcnt lgkmcnt(6)" ::: "memory");
        __builtin_amdgcn_sched_barrier(0);
        __builtin_amdgcn_s_setprio(1);
        do_mfma(mA, mB);
        __builtin_amdgcn_s_setprio(0);
        asm volatile("s_waitcnt vmcnt(3)" ::: "memory");
        __builtin_amdgcn_s_barrier();
    };

    stage(0, 0);
    stage(1, 32);
    stage(2, 64);
    asm volatile("s_waitcnt vmcnt(3)" ::: "memory");
    __builtin_amdgcn_s_barrier();

    bf16x8 afX[4], bfX[NI], afY[4], bfY[NI];
    frag_read(afX, bfX, 0);

    for (int t = 0; t < nt; t += 2) {
        do_part(afY, bfY, afX, bfX, t);
        do_part(afX, bfX, afY, bfY, t + 1);
    }

    #pragma unroll
    for (int mi = 0; mi < 4; ++mi) {
        int row = m0 + wr * 64 + mi * 16 + lh * 4;
        #pragma unroll
        for (int ni = 0; ni < NI; ++ni) {
            int col = n0 + wc * 32 + ni * 16 + lr;
            float bb = bias[col];
            #pragma unroll
            for (int r = 0; r < 4; ++r)
                H[(size_t)(row + r) * ncols + col] = f2b(fmaxf(acc[mi][ni][r] + bb, 0.f));
        }
    }
}

// ---- GEMM2: 256x320, 8 waves, BK=32, ring-2, B staged from W2 fp32 ---------
// Schedule = R7-proven body; B path converts in-flight (reg-stage, T14
// issue-early/write-late): per tile, 5x global_load_dwordx4 (fp32) issued with
// the A gload_lds, drained by ONE vmcnt(0) after both MFMA clusters (~1500cy
// cover), then cvt->ds_write_b64 into a bf16 LDS tile with the R7-exact phys
// layout (write swizzle sp=(l>>1)^((row>>1)&3) is the involution inverse of
// the verified 0-conflict read offsets; read path unchanged). Numerics
// bit-identical to cvt_w2+bf16-read (same RNE). LDS 72KB.
// WAR: slot (t+1)&1 = tile t-1's buffers; t-1's reads drained (lgkm0) before
// its end barrier, which precedes iter t's writes. Residency: vmcnt(0)+
// ds_write+lgkm(0) before the end-of-t barrier => tile t+1 fully resident.
__global__ __launch_bounds__(512) void gemm2_f(
    const unsigned short* __restrict__ A,    // hB bf16: 2048 x 1024
    const float* __restrict__ Bm,            // W2 fp32: 10000 x 1024
    const float* __restrict__ bias,
    unsigned short* __restrict__ H)          // bf16 logits 2048 x 10000
{
    __shared__ __align__(16) unsigned short lA[2][8192];    // 2 x 16KB
    __shared__ __align__(16) unsigned short lB[2][10240];   // 2 x 20KB (bf16)
    const int tid = threadIdx.x;
    const int wv = tid >> 6, ln = tid & 63;
    const int wr = wv >> 2, wc = wv & 3;        // 2M x 4N
    const int lr = ln & 15, lh = ln >> 4;

    const int nw = (blockIdx.x & 7) * 32 + (blockIdx.x >> 3);
    const int m0 = (nw & 7) * 256;
    const int n0 = (nw >> 3) * 320;

    // A staging (R7-exact, pre-swizzled source, linear LDS dest)
    const unsigned short* srcA[2];
    #pragma unroll
    for (int j = 0; j < 2; ++j) {
        int c = j * 512 + tid;
        int row = c >> 2, colL = (((c & 3) ^ ((c >> 3) & 3)) << 3);
        srcA[j] = A + (size_t)(m0 + row) * HIDDEN + colL;
    }
    // B reg-staging: 5 fp32 chunks/thread, UNSWIZZLED source (swizzle at write)
    const float* srcB[5];
    int bwr_off[5];                               // ds_write byte offsets
    #pragma unroll
    for (int j = 0; j < 5; ++j) {
        int c = j * 512 + tid;                    // 2560 chunks of 4 floats
        int row = c >> 3, l = c & 7;              // row in [0,320), l = k/4
        int gr = n0 + row; if (gr > OUT_N - 1) gr = OUT_N - 1;
        srcB[j] = Bm + (size_t)gr * HIDDEN + l * 4;
        int sp = (l >> 1) ^ ((row >> 1) & 3);     // inverse of read swizzle
        bwr_off[j] = row * 64 + sp * 16 + (l & 1) * 8;
    }

    auto stageA = [&](int slot, int kt) {
        #pragma unroll
        for (int j = 0; j < 2; ++j)
            __builtin_amdgcn_global_load_lds(
                (__attribute__((address_space(1))) const void*)(srcA[j] + kt),
                (__attribute__((address_space(3))) void*)&lA[slot][(j * 512 + tid) * 8], 16, 0, 0);
    };
    auto loadB = [&](f32x4 (&br)[5], int kt) {
        #pragma unroll
        for (int j = 0; j < 5; ++j)
            asm volatile("global_load_dwordx4 %0, %1, off"
                         : "=v"(br[j]) : "v"(srcB[j] + kt));
    };
    auto writeB = [&](f32x4 (&br)[5], int slot) {
        unsigned base = (unsigned)(unsigned long long)(lds_cp)&lB[slot][0];
        #pragma unroll
        for (int j = 0; j < 5; ++j) {
            unsigned lo = (unsigned)f2b(br[j][0]) | ((unsigned)f2b(br[j][1]) << 16);
            unsigned hi = (unsigned)f2b(br[j][2]) | ((unsigned)f2b(br[j][3]) << 16);
            u32x2 d = {lo, hi};
            unsigned ad = base + bwr_off[j];
            asm volatile("ds_write_b64 %0, %1" :: "v"(ad), "v"(d));
        }
    };

    // ds_read offsets (R7-exact, verified 0 bank conflicts)
    int a_off[8], b_off[5];
    #pragma unroll
    for (int mi = 0; mi < 8; ++mi) {
        int row = wr * 128 + mi * 16 + lr;
        a_off[mi] = (row * 64 + lh * 16) ^ (((row >> 1) & 3) << 4);
    }
    #pragma unroll
    for (int ni = 0; ni < 5; ++ni) {
        int row = wc * 80 + ni * 16 + lr;
        b_off[ni] = (row * 64 + lh * 16) ^ (((row >> 1) & 3) << 4);
    }

    f32x4 acc[8][5];
    {
        f32x4 z = {0.f, 0.f, 0.f, 0.f};
        #pragma unroll
        for (int i = 0; i < 8; ++i)
            #pragma unroll
            for (int j = 0; j < 5; ++j) acc[i][j] = z;
    }

    // prologue: tile 0
    {
        f32x4 br[5];
        stageA(0, 0);
        loadB(br, 0);
        asm volatile("s_waitcnt vmcnt(0)" ::: "memory");
        __builtin_amdgcn_sched_barrier(0);
        writeB(br, 0);
        asm volatile("s_waitcnt lgkmcnt(0)" ::: "memory");
        __builtin_amdgcn_s_barrier();
    }

    for (int t = 0; t < 32; ++t) {
        const int slot = t & 1;
        const int wsl  = (t + 1) & 1;
        int tp = t + 1; if (tp > 31) tp = 31;     // clamped re-stage, unread
        lds_cp pA = (lds_cp)&lA[slot][0];
        lds_cp pB = (lds_cp)&lB[slot][0];
        bf16x8 af[8], bfv[5];
        f32x4 br[5];

        // 13 ds_reads, ordered: B0-4, A0-7
        #pragma unroll
        for (int ni = 0; ni < 5; ++ni) {
            unsigned ad = (unsigned)(unsigned long long)pB + b_off[ni];
            asm volatile("ds_read_b128 %0, %1" : "=v"(bfv[ni]) : "v"(ad));
        }
        #pragma unroll
        for (int mi = 0; mi < 8; ++mi) {
            unsigned ad = (unsigned)(unsigned long long)pA + a_off[mi];
            asm volatile("ds_read_b128 %0, %1" : "=v"(af[mi]) : "v"(ad));
        }
        // issue tile t+1 staging early (latency hides under MFMA)
        stageA(wsl, tp * 32);
        loadB(br, tp * 32);

        // cluster lo: needs first 9 reads; 4 A-hi still in flight
        asm volatile("s_waitcnt lgkmcnt(4)" ::: "memory");
        __builtin_amdgcn_sched_barrier(0);
        __builtin_amdgcn_s_setprio(1);
        #pragma unroll
        for (int mi = 0; mi < 4; ++mi)
            #pragma unroll
            for (int ni = 0; ni < 5; ++ni)
                acc[mi][ni] = __builtin_amdgcn_mfma_f32_16x16x32_bf16(af[mi], bfv[ni], acc[mi][ni], 0, 0, 0);
        __builtin_amdgcn_s_setprio(0);

        // cluster hi
        asm volatile("s_waitcnt lgkmcnt(0)" ::: "memory");
        __builtin_amdgcn_sched_barrier(0);
        __builtin_amdgcn_s_setprio(1);
        #pragma unroll
        for (int mi = 0; mi < 4; ++mi)
            #pragma unroll
            for (int ni = 0; ni < 5; ++ni)
                acc[4 + mi][ni] = __builtin_amdgcn_mfma_f32_16x16x32_bf16(af[4 + mi], bfv[ni], acc[4 + mi][ni], 0, 0, 0);
        __builtin_amdgcn_s_setprio(0);

        // drain tile t+1 loads (covered by the 40 MFMA above), write B, publish
        asm volatile("s_waitcnt vmcnt(0)" ::: "memory");
        __builtin_amdgcn_sched_barrier(0);
        writeB(br, wsl);
        asm volatile("s_waitcnt lgkmcnt(0)" ::: "memory");
        __builtin_amdgcn_s_barrier();
    }

    // epilogue: bias + bf16 store, col-guarded
    #pragma unroll
    for (int mi = 0; mi < 8; ++mi) {
        int row = m0 + wr * 128 + mi * 16 + lh * 4;
        #pragma unroll
        for (int ni = 0; ni < 5; ++ni) {
            int col = n0 + wc * 80 + ni * 16 + lr;
            if (col < OUT_N) {
                float bb = bias[col];
                #pragma unroll
                for (int r = 0; r < 4; ++r)
                    H[(size_t)(row + r) * OUT_N + col] = f2b(acc[mi][ni][r] + bb);
            }
        }
    }
}

// ------------------------- fallback: cvt_w2 + gemm_rt -----------------------
__global__ __launch_bounds__(256) void cvt_w2(const float* __restrict__ W2,
                                              unsigned short* __restrict__ W2b) {
    size_t i = (size_t)blockIdx.x * 256 + threadIdx.x;
    if (i >= (size_t)OUT_N * HIDDEN / 8) return;
    const float4* src = (const float4*)(W2 + i * 8);
    float4 a = src[0], b = src[1];
    ushort u[8] = { f2b(a.x), f2b(a.y), f2b(a.z), f2b(a.w),
                    f2b(b.x), f2b(b.y), f2b(b.z), f2b(b.w) };
    *(uint4*)(W2b + i * 8) = *(const uint4*)u;
}

template<int NI, int MODE>
__global__ __launch_bounds__(256) void gemm_rt(
    const unsigned short* __restrict__ A,
    const unsigned short* __restrict__ Bm,
    const float* __restrict__ bias,
    void* __restrict__ outp,
    int K, int nt, int ncols, int nbm1, int nm)
{
    constexpr int BN    = 32 * NI;
    constexpr int NB_CH = NI / 2;
    __shared__ __align__(16) unsigned short lds_a[4][128 * 32];
    __shared__ __align__(16) unsigned short lds_b[4][BN * 32];

    const int tid = threadIdx.x;
    const int wv = tid >> 6, ln = tid & 63;
    const int wr = wv >> 1, wc = wv & 1;
    const int lr = ln & 15, lh = ln >> 4;

    const int g   = gridDim.x;
    const int nw  = (blockIdx.x & 7) * (g >> 3) + (blockIdx.x >> 3);
    const int mt  = nw % nm, ntile = nw / nm;
    const int m0  = mt * 128, n0 = ntile * BN;

    const unsigned short* srcA[2];
    const unsigned short* srcB[NB_CH];
    #pragma unroll
    for (int i = 0; i < 2; ++i) {
        int c = tid + i * 256;
        int row = c >> 2, colL = (((c & 3) ^ ((c >> 3) & 3)) << 3);
        srcA[i] = A + (size_t)(m0 + row) * K + colL;
    }
    #pragma unroll
    for (int j = 0; j < NB_CH; ++j) {
        int c = tid + j * 256;
        int row = c >> 2, colL = (((c & 3) ^ ((c >> 3) & 3)) << 3);
        int gr = n0 + row; if (gr > nbm1) gr = nbm1;
        srcB[j] = Bm + (size_t)gr * K + colL;
    }

    auto stage = [&](int buf, int kt) {
        #pragma unroll
        for (int i = 0; i < 2; ++i)
            __builtin_amdgcn_global_load_lds(
                (__attribute__((address_space(1))) const void*)(srcA[i] + kt),
                (__attribute__((address_space(3))) void*)&lds_a[buf][(tid + i * 256) * 8], 16, 0, 0);
        #pragma unroll
        for (int j = 0; j < NB_CH; ++j)
            __builtin_amdgcn_global_load_lds(
                (__attribute__((address_space(1))) const void*)(srcB[j] + kt),
                (__attribute__((address_space(3))) void*)&lds_b[buf][(tid + j * 256) * 8], 16, 0, 0);
    };

    int a_off[4], b_off[NI];
    #pragma unroll
    for (int mi = 0; mi < 4; ++mi) {
        int row = wr * 64 + mi * 16 + lr;
        a_off[mi] = (row * 64 + lh * 16) ^ (((row >> 1) & 3) << 4);
    }
    #pragma unroll
    for (int ni = 0; ni < NI; ++ni) {
        int row = wc * 16 * NI + ni * 16 + lr;
        b_off[ni] = (row * 64 + lh * 16) ^ (((row >> 1) & 3) << 4);
    }

    f32x4 acc[4][NI];
    {
        f32x4 z = {0.f, 0.f, 0.f, 0.f};
        #pragma unroll
        for (int i = 0; i < 4; ++i)
            #pragma unroll
            for (int j = 0; j < NI; ++j) acc[i][j] = z;
    }

    auto frag_read = [&](bf16x8 (&af)[4], bf16x8 (&bfv)[NI], int buf) {
        lds_cp pa = (lds_cp)&lds_a[buf][0];
        lds_cp pb = (lds_cp)&lds_b[buf][0];
        #pragma unroll
        for (int mi = 0; mi < 4; ++mi) {
            unsigned ad = (unsigned)(unsigned long long)pa + a_off[mi];
            asm volatile("ds_read_b128 %0, %1" : "=v"(af[mi]) : "v"(ad));
        }
        #pragma unroll
        for (int ni = 0; ni < NI; ++ni) {
            unsigned ad = (unsigned)(unsigned long long)pb + b_off[ni];
            asm volatile("ds_read_b128 %0, %1" : "=v"(bfv[ni]) : "v"(ad));
        }
    };
    auto do_mfma = [&](bf16x8 (&af)[4], bf16x8 (&bfv)[NI]) {
        #pragma unroll
        for (int mi = 0; mi < 4; ++mi)
            #pragma unroll
            for (int ni = 0; ni < NI; ++ni)
                acc[mi][ni] = __builtin_amdgcn_mfma_f32_16x16x32_bf16(af[mi], bfv[ni], acc[mi][ni], 0, 0, 0);
    };
    auto do_part = [&](bf16x8 (&rA)[4], bf16x8 (&rB)[NI],
                       bf16x8 (&mA)[4], bf16x8 (&mB)[NI], int p) {
        frag_read(rA, rB, (p + 1) & 3);
        int tp = p + 3; if (tp > nt - 1) tp = nt - 1;
        stage((p + 3) & 3, tp * 32);
        if constexpr (NI == 4) asm volatile("s_waitcnt lgkmcnt(8)" ::: "memory");
        else                   asm volatile("s_waitcnt lgkmcnt(6)" ::: "memory");
        __builtin_amdgcn_sched_barrier(0);
        __builtin_amdgcn_s_setprio(1);
        do_mfma(mA, mB);
        __builtin_amdgcn_s_setprio(0);
        if constexpr (NI == 4) asm volatile("s_waitcnt vmcnt(4)" ::: "memory");
        else                   asm volatile("s_waitcnt vmcnt(3)" ::: "memory");
        __builtin_amdgcn_s_barrier();
    };

    stage(0, 0);
    stage(1, 32);
    stage(2, 64);
    if constexpr (NI == 4) asm volatile("s_waitcnt vmcnt(4)" ::: "memory");
    else                   asm volatile("s_waitcnt vmcnt(3)" ::: "memory");
    __builtin_amdgcn_s_barrier();

    bf16x8 afX[4], bfX[NI], afY[4], bfY[NI];
    frag_read(afX, bfX, 0);

    for (int t = 0; t < nt; t += 2) {
        do_part(afY, bfY, afX, bfX, t);
        do_part(afX, bfX, afY, bfY, t + 1);
    }

    #pragma unroll
    for (int mi = 0; mi < 4; ++mi) {
        int row = m0 + wr * 64 + mi * 16 + lh * 4;
        #pragma unroll
        for (int ni = 0; ni < NI; ++ni) {
            int col = n0 + wc * 16 * NI + ni * 16 + lr;
            if (col < ncols) {
                float bb = bias[col];
                if (MODE == 0) {
                    unsigned short* H = (unsigned short*)outp;
                    #pragma unroll
                    for (int r = 0; r < 4; ++r)
                        H[(size_t)(row + r) * ncols + col] = f2b(fmaxf(acc[mi][ni][r] + bb, 0.f));
                } else {
                    float* O = (float*)outp;
                    #pragma unroll
                    for (int r = 0; r < 4; ++r)
                        O[(size_t)(row + r) * ncols + col] = acc[mi][ni][r] + bb;
                }
            }
        }
    }
}

// ---------- logsoftmax, bf16 logits: SINGLE-PASS online max/sum-exp ----------
__global__ __launch_bounds__(256) void lsm_b(const unsigned short* __restrict__ lg,
                                             float* __restrict__ out) {
    __shared__ __align__(16) uint4 rowbuf[1250];   // 10000 bf16 raw
    __shared__ float redm[4], reds[4];
    __shared__ float s_lz;
    const int t = threadIdx.x, wv = t >> 6, ln = t & 63;
    const unsigned short* l = lg + (size_t)blockIdx.x * OUT_N;
    float* o = out + (size_t)blockIdx.x * OUT_N;

    float m = -3.4e38f, s = 0.f;
    for (int i = t; i < 1250; i += 256) {
        uint4 v = ((const uint4*)l)[i];
        rowbuf[i] = v;
        unsigned w[4] = {v.x, v.y, v.z, v.w};
        float f[8];
        #pragma unroll
        for (int j = 0; j < 4; ++j) {
            f[2*j]   = __builtin_bit_cast(float, w[j] << 16);
            f[2*j+1] = __builtin_bit_cast(float, w[j] & 0xffff0000u);
        }
        float cm = fmaxf(fmaxf(fmaxf(f[0], f[1]), fmaxf(f[2], f[3])),
                         fmaxf(fmaxf(f[4], f[5]), fmaxf(f[6], f[7])));
        if (cm > m) { s *= __expf(m - cm); m = cm; }
        #pragma unroll
        for (int j = 0; j < 8; ++j) s += __expf(f[j] - m);
    }
    #pragma unroll
    for (int off = 32; off > 0; off >>= 1) {
        float om = __shfl_xor(m, off, 64);
        float os = __shfl_xor(s, off, 64);
        float nm = fmaxf(m, om);
        s = s * __expf(m - nm) + os * __expf(om - nm);
        m = nm;
    }
    if (ln == 0) { redm[wv] = m; reds[wv] = s; }
    __syncthreads();
    if (t == 0) {
        float gm = fmaxf(fmaxf(redm[0], redm[1]), fmaxf(redm[2], redm[3]));
        float gs = reds[0] * __expf(redm[0] - gm) + reds[1] * __expf(redm[1] - gm)
                 + reds[2] * __expf(redm[2] - gm) + reds[3] * __expf(redm[3] - gm);
        s_lz = gm + logf(gs);
    }
    __syncthreads();
    const float lz = s_lz;

    for (int i = t; i < 1250; i += 256) {
        uint4 v = rowbuf[i];
        unsigned w[4] = {v.x, v.y, v.z, v.w};
        float4 o0, o1;
        o0.x = __builtin_bit_cast(float, w[0] << 16)          - lz;
        o0.y = __builtin_bit_cast(float, w[0] & 0xffff0000u)  - lz;
        o0.z = __builtin_bit_cast(float, w[1] << 16)          - lz;
        o0.w = __builtin_bit_cast(float, w[1] & 0xffff0000u)  - lz;
        o1.x = __builtin_bit_cast(float, w[2] << 16)          - lz;
        o1.y = __builtin_bit_cast(float, w[2] & 0xffff0000u)  - lz;
        o1.z = __builtin_bit_cast(float, w[3] << 16)          - lz;
        o1.w = __builtin_bit_cast(float, w[3] & 0xffff0000u)  - lz;
        ((float4*)o)[2 * i]     = o0;
        ((float4*)o)[2 * i + 1] = o1;
    }
}

// --------------------------------------------- logsoftmax, fp32 in-place ---
__global__ __launch_bounds__(256) void lsm_f(float* __restrict__ out) {
    __shared__ __align__(16) float rowbuf[OUT_N];
    __shared__ float red[8];
    const int t = threadIdx.x, wv = t >> 6, ln = t & 63;
    float* o = out + (size_t)blockIdx.x * OUT_N;

    float mx = -3.4e38f;
    for (int i = t; i < OUT_N / 4; i += 256) {
        float4 v = ((const float4*)o)[i];
        rowbuf[i*4] = v.x; rowbuf[i*4+1] = v.y; rowbuf[i*4+2] = v.z; rowbuf[i*4+3] = v.w;
        mx = fmaxf(fmaxf(mx, fmaxf(v.x, v.y)), fmaxf(v.z, v.w));
    }
    #pragma unroll
    for (int off = 32; off > 0; off >>= 1) mx = fmaxf(mx, __shfl_xor(mx, off, 64));
    if (ln == 0) red[wv] = mx;
    __syncthreads();
    float m4 = fmaxf(fmaxf(red[0], red[1]), fmaxf(red[2], red[3]));

    float s = 0.f;
    for (int i = t; i < OUT_N; i += 256) s += __expf(rowbuf[i] - m4);
    #pragma unroll
    for (int off = 32; off > 0; off >>= 1) s += __shfl_xor(s, off, 64);
    if (ln == 0) red[4 + wv] = s;
    __syncthreads();
    float lz = m4 + logf(red[4] + red[5] + red[6] + red[7]);

    for (int i = t; i < OUT_N / 4; i += 256) {
        float4 v = { rowbuf[i*4] - lz, rowbuf[i*4+1] - lz,
                     rowbuf[i*4+2] - lz, rowbuf[i*4+3] - lz };
        ((float4*)o)[i] = v;
    }
}

// ----------------------------------------------------------------- launch ---
extern "C" void kernel_launch(void* const* d_in, const int* in_sizes, int n_in,
                              void* d_out, int out_size, void* d_ws, size_t ws_size,
                              hipStream_t stream) {
    const float* d_onehot    = (const float*)d_in[0];
    const int*   cat_ix      = (const int*)  d_in[1];
    const int*   hvb_ix      = (const int*)  d_in[2];
    const int*   hvf_ix      = (const int*)  d_in[3];
    const float* hvb_top     = (const float*)d_in[4];
    const float* hvf_top     = (const float*)d_in[5];
    const float* cat_embeds  = (const float*)d_in[6];
    const float* hvec_embeds = (const float*)d_in[7];
    const float* W1          = (const float*)d_in[8];
    const float* b1          = (const float*)d_in[9];
    const float* W2          = (const float*)d_in[10];
    const float* b2          = (const float*)d_in[11];
    float* out = (float*)d_out;

    unsigned short* xb  = (unsigned short*)d_ws;               // 2048 x 704
    unsigned short* W1b = xb  + (size_t)B_ * K1;               // 1024 x 704
    unsigned short* hB  = W1b + (size_t)HIDDEN * K1;           // 2048 x 1024
    unsigned short* lg  = hB  + (size_t)B_ * HIDDEN;           // 2048 x 10000 bf16 logits
    const size_t need = ((size_t)B_*K1 + (size_t)HIDDEN*K1 + (size_t)B_*HIDDEN
                         + (size_t)B_*OUT_N) * 2;
    const bool bf16_logits = (ws_size >= need);

    prep_light<<<dim3(NB_W1 + B_), dim3(256), 0, stream>>>(
        W1, W1b, d_onehot, cat_ix, hvb_ix, hvf_ix,
        hvb_top, hvf_top, cat_embeds, hvec_embeds, xb);
    mid<<<dim3(256), dim3(256), 0, stream>>>(xb, W1b, b1, hB);
    if (bf16_logits) {
        gemm2_f<<<dim3(256), dim3(512), 0, stream>>>(hB, W2, b2, lg);
        lsm_b<<<dim3(B_), dim3(256), 0, stream>>>(lg, out);
    } else {
        unsigned short* W2b = lg;  // reuse region (no lg in fallback)
        cvt_w2<<<dim3((OUT_N * HIDDEN / 8 + 255) / 256), dim3(256), 0, stream>>>(W2, W2b);
        gemm_rt<4, 2><<<dim3(16 * 79), dim3(256), 0, stream>>>(
            hB, W2b, b2, (void*)out, HIDDEN, HIDDEN / 32, OUT_N, OUT_N - 1, 16);
        lsm_f<<<dim3(B_), dim3(256), 0, stream>>>(out);
    }
}

// Round 12
// 96.923 us; speedup vs baseline: 1.1894x; 1.1894x over previous
//
#include <hip/hip_runtime.h>

#define B_      2048
#define SYN     128
#define SEM     256
#define IN_DIM  647
#define K1      704      // 647 padded to 22*32
#define HIDDEN  1024
#define OUT_N   10000
#define NNZ     8

typedef __bf16 bf16x8 __attribute__((ext_vector_type(8)));
typedef float  f32x4  __attribute__((ext_vector_type(4)));
typedef __attribute__((address_space(3))) const unsigned short* lds_cp;

__device__ __forceinline__ unsigned short f2b(float v) {
    __bf16 b = (__bf16)v;
    return __builtin_bit_cast(unsigned short, b);
}

// --------------------- prep_light: cvt_w1 + build_x only --------------------
#define NB_W1 2816   // HIDDEN*K1/256
#define NB_W2 5000   // OUT_N*HIDDEN/8/256
__global__ __launch_bounds__(256) void prep_light(
    const float* __restrict__ W1,  unsigned short* __restrict__ W1b,
    const float* __restrict__ d_onehot,
    const int*   __restrict__ cat_ix,
    const int*   __restrict__ hvb_ix,
    const int*   __restrict__ hvf_ix,
    const float* __restrict__ hvb_top,
    const float* __restrict__ hvf_top,
    const float* __restrict__ cat_embeds,
    const float* __restrict__ hvec_embeds,
    unsigned short* __restrict__ xb)
{
    const int bb = blockIdx.x, t = threadIdx.x;
    if (bb < NB_W1) {
        int idx = bb * 256 + t;
        int r = idx / K1, c = idx - r * K1;
        W1b[idx] = f2b(c < IN_DIM ? W1[r * IN_DIM + c] : 0.f);
        return;
    }
    const int b = bb - NB_W1;
    unsigned short* xrow = xb + (size_t)b * K1;
    if (t < SYN) {
        int c = cat_ix[b];
        xrow[t] = f2b(cat_embeds[(size_t)c * SYN + t]);
    }
    {
        int ix[NNZ];
        #pragma unroll
        for (int j = 0; j < NNZ; ++j) ix[j] = hvb_ix[b * NNZ + j];
        float s = hvb_top[(size_t)b * SEM + t];
        #pragma unroll
        for (int j = 0; j < NNZ; ++j) {
            bool dup = false;
            for (int k2 = 0; k2 < j; ++k2) dup = dup || (ix[j] == ix[k2]);
            if (!dup) s += hvec_embeds[(size_t)ix[j] * SEM + t];
        }
        xrow[SYN + t] = f2b(s);
    }
    {
        int ix[NNZ];
        #pragma unroll
        for (int j = 0; j < NNZ; ++j) ix[j] = hvf_ix[b * NNZ + j];
        float s = hvf_top[(size_t)b * SEM + t];
        #pragma unroll
        for (int j = 0; j < NNZ; ++j) {
            bool dup = false;
            for (int k2 = 0; k2 < j; ++k2) dup = dup || (ix[j] == ix[k2]);
            if (!dup) s += hvec_embeds[(size_t)ix[j] * SEM + t];
        }
        xrow[SYN + SEM + t] = f2b(s);
    }
    if (t < 7)       xrow[640 + t] = f2b(d_onehot[b * 7 + t]);
    else if (t < 64) xrow[640 + t] = 0;
}

// ---------- mid: heterogeneous grid = GEMM1 (blocks 0-255) + cvt_w2 ---------
__global__ __launch_bounds__(256) void mid(
    const unsigned short* __restrict__ A,    // xb
    const unsigned short* __restrict__ Bm,   // W1b
    const float* __restrict__ bias,          // b1
    unsigned short* __restrict__ H,          // hB
    const float* __restrict__ W2,
    unsigned short* __restrict__ W2b)
{
    if (blockIdx.x >= 256) {
        size_t i = (size_t)(blockIdx.x - 256) * 256 + threadIdx.x;   // 8-elem group
        const float4* src = (const float4*)(W2 + i * 8);
        float4 a = src[0], b = src[1];
        ushort u[8] = { f2b(a.x), f2b(a.y), f2b(a.z), f2b(a.w),
                        f2b(b.x), f2b(b.y), f2b(b.z), f2b(b.w) };
        *(uint4*)(W2b + i * 8) = *(const uint4*)u;
        return;
    }

    constexpr int NI = 2, nt = K1 / 32, K = K1, ncols = HIDDEN, nbm1 = HIDDEN - 1;
    __shared__ __align__(16) unsigned short lds_a[4][128 * 32];
    __shared__ __align__(16) unsigned short lds_b[4][64 * 32];

    const int tid = threadIdx.x;
    const int wv = tid >> 6, ln = tid & 63;
    const int wr = wv >> 1, wc = wv & 1;
    const int lr = ln & 15, lh = ln >> 4;

    const int vbid = blockIdx.x;
    const int nw  = (vbid & 7) * 32 + (vbid >> 3);
    const int mt  = nw % 16, ntile = nw / 16;
    const int m0  = mt * 128, n0 = ntile * 64;

    const unsigned short* srcA[2];
    const unsigned short* srcB0;
    #pragma unroll
    for (int i = 0; i < 2; ++i) {
        int c = tid + i * 256;
        int row = c >> 2, colL = (((c & 3) ^ ((c >> 3) & 3)) << 3);
        srcA[i] = A + (size_t)(m0 + row) * K + colL;
    }
    {
        int c = tid;
        int row = c >> 2, colL = (((c & 3) ^ ((c >> 3) & 3)) << 3);
        int gr = n0 + row; if (gr > nbm1) gr = nbm1;
        srcB0 = Bm + (size_t)gr * K + colL;
    }

    auto stage = [&](int buf, int kt) {
        #pragma unroll
        for (int i = 0; i < 2; ++i)
            __builtin_amdgcn_global_load_lds(
                (__attribute__((address_space(1))) const void*)(srcA[i] + kt),
                (__attribute__((address_space(3))) void*)&lds_a[buf][(tid + i * 256) * 8], 16, 0, 0);
        __builtin_amdgcn_global_load_lds(
            (__attribute__((address_space(1))) const void*)(srcB0 + kt),
            (__attribute__((address_space(3))) void*)&lds_b[buf][tid * 8], 16, 0, 0);
    };

    int a_off[4], b_off[NI];
    #pragma unroll
    for (int mi = 0; mi < 4; ++mi) {
        int row = wr * 64 + mi * 16 + lr;
        a_off[mi] = (row * 64 + lh * 16) ^ (((row >> 1) & 3) << 4);
    }
    #pragma unroll
    for (int ni = 0; ni < NI; ++ni) {
        int row = wc * 32 + ni * 16 + lr;
        b_off[ni] = (row * 64 + lh * 16) ^ (((row >> 1) & 3) << 4);
    }

    f32x4 acc[4][NI];
    {
        f32x4 z = {0.f, 0.f, 0.f, 0.f};
        #pragma unroll
        for (int i = 0; i < 4; ++i)
            #pragma unroll
            for (int j = 0; j < NI; ++j) acc[i][j] = z;
    }

    auto frag_read = [&](bf16x8 (&af)[4], bf16x8 (&bfv)[NI], int buf) {
        lds_cp pa = (lds_cp)&lds_a[buf][0];
        lds_cp pb = (lds_cp)&lds_b[buf][0];
        #pragma unroll
        for (int mi = 0; mi < 4; ++mi) {
            unsigned ad = (unsigned)(unsigned long long)pa + a_off[mi];
            asm volatile("ds_read_b128 %0, %1" : "=v"(af[mi]) : "v"(ad));
        }
        #pragma unroll
        for (int ni = 0; ni < NI; ++ni) {
            unsigned ad = (unsigned)(unsigned long long)pb + b_off[ni];
            asm volatile("ds_read_b128 %0, %1" : "=v"(bfv[ni]) : "v"(ad));
        }
    };
    auto do_mfma = [&](bf16x8 (&af)[4], bf16x8 (&bfv)[NI]) {
        #pragma unroll
        for (int mi = 0; mi < 4; ++mi)
            #pragma unroll
            for (int ni = 0; ni < NI; ++ni)
                acc[mi][ni] = __builtin_amdgcn_mfma_f32_16x16x32_bf16(af[mi], bfv[ni], acc[mi][ni], 0, 0, 0);
    };
    auto do_part = [&](bf16x8 (&rA)[4], bf16x8 (&rB)[NI],
                       bf16x8 (&mA)[4], bf16x8 (&mB)[NI], int p) {
        frag_read(rA, rB, (p + 1) & 3);
        int tp = p + 3; if (tp > nt - 1) tp = nt - 1;
        stage((p + 3) & 3, tp * 32);
        asm volatile("s_waitcnt lgkmcnt(6)" ::: "memory");
        __builtin_amdgcn_sched_barrier(0);
        __builtin_amdgcn_s_setprio(1);
        do_mfma(mA, mB);
        __builtin_amdgcn_s_setprio(0);
        asm volatile("s_waitcnt vmcnt(3)" ::: "memory");
        __builtin_amdgcn_s_barrier();
    };

    stage(0, 0);
    stage(1, 32);
    stage(2, 64);
    asm volatile("s_waitcnt vmcnt(3)" ::: "memory");
    __builtin_amdgcn_s_barrier();

    bf16x8 afX[4], bfX[NI], afY[4], bfY[NI];
    frag_read(afX, bfX, 0);

    for (int t = 0; t < nt; t += 2) {
        do_part(afY, bfY, afX, bfX, t);
        do_part(afX, bfX, afY, bfY, t + 1);
    }

    #pragma unroll
    for (int mi = 0; mi < 4; ++mi) {
        int row = m0 + wr * 64 + mi * 16 + lh * 4;
        #pragma unroll
        for (int ni = 0; ni < NI; ++ni) {
            int col = n0 + wc * 32 + ni * 16 + lr;
            float bb = bias[col];
            #pragma unroll
            for (int r = 0; r < 4; ++r)
                H[(size_t)(row + r) * ncols + col] = f2b(fmaxf(acc[mi][ni][r] + bb, 0.f));
        }
    }
}

// ----------------------- fallback GEMM template (fp32 out) ------------------
template<int NI, int MODE>
__global__ __launch_bounds__(256) void gemm_rt(
    const unsigned short* __restrict__ A,
    const unsigned short* __restrict__ Bm,
    const float* __restrict__ bias,
    void* __restrict__ outp,
    int K, int nt, int ncols, int nbm1, int nm)
{
    constexpr int BN    = 32 * NI;
    constexpr int NB_CH = NI / 2;
    __shared__ __align__(16) unsigned short lds_a[4][128 * 32];
    __shared__ __align__(16) unsigned short lds_b[4][BN * 32];

    const int tid = threadIdx.x;
    const int wv = tid >> 6, ln = tid & 63;
    const int wr = wv >> 1, wc = wv & 1;
    const int lr = ln & 15, lh = ln >> 4;

    const int g   = gridDim.x;
    const int nw  = (blockIdx.x & 7) * (g >> 3) + (blockIdx.x >> 3);
    const int mt  = nw % nm, ntile = nw / nm;
    const int m0  = mt * 128, n0 = ntile * BN;

    const unsigned short* srcA[2];
    const unsigned short* srcB[NB_CH];
    #pragma unroll
    for (int i = 0; i < 2; ++i) {
        int c = tid + i * 256;
        int row = c >> 2, colL = (((c & 3) ^ ((c >> 3) & 3)) << 3);
        srcA[i] = A + (size_t)(m0 + row) * K + colL;
    }
    #pragma unroll
    for (int j = 0; j < NB_CH; ++j) {
        int c = tid + j * 256;
        int row = c >> 2, colL = (((c & 3) ^ ((c >> 3) & 3)) << 3);
        int gr = n0 + row; if (gr > nbm1) gr = nbm1;
        srcB[j] = Bm + (size_t)gr * K + colL;
    }

    auto stage = [&](int buf, int kt) {
        #pragma unroll
        for (int i = 0; i < 2; ++i)
            __builtin_amdgcn_global_load_lds(
                (__attribute__((address_space(1))) const void*)(srcA[i] + kt),
                (__attribute__((address_space(3))) void*)&lds_a[buf][(tid + i * 256) * 8], 16, 0, 0);
        #pragma unroll
        for (int j = 0; j < NB_CH; ++j)
            __builtin_amdgcn_global_load_lds(
                (__attribute__((address_space(1))) const void*)(srcB[j] + kt),
                (__attribute__((address_space(3))) void*)&lds_b[buf][(tid + j * 256) * 8], 16, 0, 0);
    };

    int a_off[4], b_off[NI];
    #pragma unroll
    for (int mi = 0; mi < 4; ++mi) {
        int row = wr * 64 + mi * 16 + lr;
        a_off[mi] = (row * 64 + lh * 16) ^ (((row >> 1) & 3) << 4);
    }
    #pragma unroll
    for (int ni = 0; ni < NI; ++ni) {
        int row = wc * 16 * NI + ni * 16 + lr;
        b_off[ni] = (row * 64 + lh * 16) ^ (((row >> 1) & 3) << 4);
    }

    f32x4 acc[4][NI];
    {
        f32x4 z = {0.f, 0.f, 0.f, 0.f};
        #pragma unroll
        for (int i = 0; i < 4; ++i)
            #pragma unroll
            for (int j = 0; j < NI; ++j) acc[i][j] = z;
    }

    auto frag_read = [&](bf16x8 (&af)[4], bf16x8 (&bfv)[NI], int buf) {
        lds_cp pa = (lds_cp)&lds_a[buf][0];
        lds_cp pb = (lds_cp)&lds_b[buf][0];
        #pragma unroll
        for (int mi = 0; mi < 4; ++mi) {
            unsigned ad = (unsigned)(unsigned long long)pa + a_off[mi];
            asm volatile("ds_read_b128 %0, %1" : "=v"(af[mi]) : "v"(ad));
        }
        #pragma unroll
        for (int ni = 0; ni < NI; ++ni) {
            unsigned ad = (unsigned)(unsigned long long)pb + b_off[ni];
            asm volatile("ds_read_b128 %0, %1" : "=v"(bfv[ni]) : "v"(ad));
        }
    };
    auto do_mfma = [&](bf16x8 (&af)[4], bf16x8 (&bfv)[NI]) {
        #pragma unroll
        for (int mi = 0; mi < 4; ++mi)
            #pragma unroll
            for (int ni = 0; ni < NI; ++ni)
                acc[mi][ni] = __builtin_amdgcn_mfma_f32_16x16x32_bf16(af[mi], bfv[ni], acc[mi][ni], 0, 0, 0);
    };
    auto do_part = [&](bf16x8 (&rA)[4], bf16x8 (&rB)[NI],
                       bf16x8 (&mA)[4], bf16x8 (&mB)[NI], int p) {
        frag_read(rA, rB, (p + 1) & 3);
        int tp = p + 3; if (tp > nt - 1) tp = nt - 1;
        stage((p + 3) & 3, tp * 32);
        if constexpr (NI == 4) asm volatile("s_waitcnt lgkmcnt(8)" ::: "memory");
        else                   asm volatile("s_waitcnt lgkmcnt(6)" ::: "memory");
        __builtin_amdgcn_sched_barrier(0);
        __builtin_amdgcn_s_setprio(1);
        do_mfma(mA, mB);
        __builtin_amdgcn_s_setprio(0);
        if constexpr (NI == 4) asm volatile("s_waitcnt vmcnt(4)" ::: "memory");
        else                   asm volatile("s_waitcnt vmcnt(3)" ::: "memory");
        __builtin_amdgcn_s_barrier();
    };

    stage(0, 0);
    stage(1, 32);
    stage(2, 64);
    if constexpr (NI == 4) asm volatile("s_waitcnt vmcnt(4)" ::: "memory");
    else                   asm volatile("s_waitcnt vmcnt(3)" ::: "memory");
    __builtin_amdgcn_s_barrier();

    bf16x8 afX[4], bfX[NI], afY[4], bfY[NI];
    frag_read(afX, bfX, 0);

    for (int t = 0; t < nt; t += 2) {
        do_part(afY, bfY, afX, bfX, t);
        do_part(afX, bfX, afY, bfY, t + 1);
    }

    #pragma unroll
    for (int mi = 0; mi < 4; ++mi) {
        int row = m0 + wr * 64 + mi * 16 + lh * 4;
        #pragma unroll
        for (int ni = 0; ni < NI; ++ni) {
            int col = n0 + wc * 16 * NI + ni * 16 + lr;
            if (col < ncols) {
                float bb = bias[col];
                if (MODE == 0) {
                    unsigned short* H = (unsigned short*)outp;
                    #pragma unroll
                    for (int r = 0; r < 4; ++r)
                        H[(size_t)(row + r) * ncols + col] = f2b(fmaxf(acc[mi][ni][r] + bb, 0.f));
                } else {
                    float* O = (float*)outp;
                    #pragma unroll
                    for (int r = 0; r < 4; ++r)
                        O[(size_t)(row + r) * ncols + col] = acc[mi][ni][r] + bb;
                }
            }
        }
    }
}

// ---- GEMM2 (R7-exact best: 256x320, ring-4, merged barrier, vmcnt(10)) ----
__global__ __launch_bounds__(512, 2) void gemm2_m(
    const unsigned short* __restrict__ A,    // hB: 2048 x 1024
    const unsigned short* __restrict__ Bm,   // W2b: 10000 x 1024
    const float* __restrict__ bias,
    unsigned short* __restrict__ H)          // bf16 logits 2048 x 10000
{
    __shared__ __align__(16) unsigned short lA[4][8192];    // 4 x 16KB
    __shared__ __align__(16) unsigned short lB[4][10240];   // 4 x 20KB
    const int tid = threadIdx.x;
    const int wv = tid >> 6, ln = tid & 63;
    const int wr = wv >> 2, wc = wv & 3;        // 2M x 4N
    const int lr = ln & 15, lh = ln >> 4;

    const int nw = (blockIdx.x & 7) * 32 + (blockIdx.x >> 3);
    const int m0 = (nw & 7) * 256;
    const int n0 = (nw >> 3) * 320;

    const unsigned short* srcA[2];
    const unsigned short* srcB[2];
    const unsigned short* srcB2;
    #pragma unroll
    for (int j = 0; j < 2; ++j) {
        int c = j * 512 + tid;
        int row = c >> 2, colL = (((c & 3) ^ ((c >> 3) & 3)) << 3);
        srcA[j] = A + (size_t)(m0 + row) * HIDDEN + colL;
        int gr = n0 + row; if (gr > OUT_N - 1) gr = OUT_N - 1;
        srcB[j] = Bm + (size_t)gr * HIDDEN + colL;
    }
    const int c2 = 1024 + (wv & 3) * 64 + ln;   // waves 4-7 duplicate 0-3 (benign)
    {
        int row = c2 >> 2, colL = (((c2 & 3) ^ ((c2 >> 3) & 3)) << 3);
        int gr = n0 + row; if (gr > OUT_N - 1) gr = OUT_N - 1;
        srcB2 = Bm + (size_t)gr * HIDDEN + colL;
    }

    auto stageA = [&](int slot, int kt) {
        #pragma unroll
        for (int j = 0; j < 2; ++j)
            __builtin_amdgcn_global_load_lds(
                (__attribute__((address_space(1))) const void*)(srcA[j] + kt),
                (__attribute__((address_space(3))) void*)&lA[slot][(j * 512 + tid) * 8], 16, 0, 0);
    };
    auto stageB = [&](int slot, int kt) {
        #pragma unroll
        for (int j = 0; j < 2; ++j)
            __builtin_amdgcn_global_load_lds(
                (__attribute__((address_space(1))) const void*)(srcB[j] + kt),
                (__attribute__((address_space(3))) void*)&lB[slot][(j * 512 + tid) * 8], 16, 0, 0);
        __builtin_amdgcn_global_load_lds(
            (__attribute__((address_space(1))) const void*)(srcB2 + kt),
            (__attribute__((address_space(3))) void*)&lB[slot][c2 * 8], 16, 0, 0);
    };

    int a_off[8], b_off[5];
    #pragma unroll
    for (int mi = 0; mi < 8; ++mi) {
        int row = wr * 128 + mi * 16 + lr;
        a_off[mi] = (row * 64 + lh * 16) ^ (((row >> 1) & 3) << 4);
    }
    #pragma unroll
    for (int ni = 0; ni < 5; ++ni) {
        int row = wc * 80 + ni * 16 + lr;
        b_off[ni] = (row * 64 + lh * 16) ^ (((row >> 1) & 3) << 4);
    }

    f32x4 acc[8][5];
    {
        f32x4 z = {0.f, 0.f, 0.f, 0.f};
        #pragma unroll
        for (int i = 0; i < 8; ++i)
            #pragma unroll
            for (int j = 0; j < 5; ++j) acc[i][j] = z;
    }

    stageA(0, 0);  stageB(0, 0);
    stageA(1, 32); stageB(1, 32);
    stageA(2, 64); stageB(2, 64);
    asm volatile("s_waitcnt vmcnt(10)" ::: "memory");
    __builtin_amdgcn_s_barrier();

    for (int t = 0; t < 32; ++t) {
        const int slot = t & 3;
        const int wsl  = (t + 3) & 3;
        int tp = t + 3; if (tp > 31) tp = 31;
        lds_cp pA = (lds_cp)&lA[slot][0];
        lds_cp pB = (lds_cp)&lB[slot][0];
        bf16x8 af[8], bfv[5];

        #pragma unroll
        for (int ni = 0; ni < 5; ++ni) {
            unsigned ad = (unsigned)(unsigned long long)pB + b_off[ni];
            asm volatile("ds_read_b128 %0, %1" : "=v"(bfv[ni]) : "v"(ad));
        }
        #pragma unroll
        for (int mi = 0; mi < 8; ++mi) {
            unsigned ad = (unsigned)(unsigned long long)pA + a_off[mi];
            asm volatile("ds_read_b128 %0, %1" : "=v"(af[mi]) : "v"(ad));
        }
        stageA(wsl, tp * 32);
        stageB(wsl, tp * 32);

        asm volatile("s_waitcnt lgkmcnt(4)" ::: "memory");
        __builtin_amdgcn_sched_barrier(0);
        __builtin_amdgcn_s_setprio(1);
        #pragma unroll
        for (int mi = 0; mi < 4; ++mi)
            #pragma unroll
            for (int ni = 0; ni < 5; ++ni)
                acc[mi][ni] = __builtin_amdgcn_mfma_f32_16x16x32_bf16(af[mi], bfv[ni], acc[mi][ni], 0, 0, 0);
        __builtin_amdgcn_s_setprio(0);

        asm volatile("s_waitcnt lgkmcnt(0)" ::: "memory");
        __builtin_amdgcn_sched_barrier(0);
        __builtin_amdgcn_s_setprio(1);
        #pragma unroll
        for (int mi = 0; mi < 4; ++mi)
            #pragma unroll
            for (int ni = 0; ni < 5; ++ni)
                acc[4 + mi][ni] = __builtin_amdgcn_mfma_f32_16x16x32_bf16(af[4 + mi], bfv[ni], acc[4 + mi][ni], 0, 0, 0);
        __builtin_amdgcn_s_setprio(0);

        asm volatile("s_waitcnt vmcnt(10)" ::: "memory");
        __builtin_amdgcn_s_barrier();
    }

    #pragma unroll
    for (int mi = 0; mi < 8; ++mi) {
        int row = m0 + wr * 128 + mi * 16 + lh * 4;
        #pragma unroll
        for (int ni = 0; ni < 5; ++ni) {
            int col = n0 + wc * 80 + ni * 16 + lr;
            if (col < OUT_N) {
                float bb = bias[col];
                #pragma unroll
                for (int r = 0; r < 4; ++r)
                    H[(size_t)(row + r) * OUT_N + col] = f2b(acc[mi][ni][r] + bb);
            }
        }
    }
}

// ---------- logsoftmax, bf16 logits: SINGLE-PASS online max/sum-exp ----------
__global__ __launch_bounds__(256) void lsm_b(const unsigned short* __restrict__ lg,
                                             float* __restrict__ out) {
    __shared__ __align__(16) uint4 rowbuf[1250];   // 10000 bf16 raw
    __shared__ float redm[4], reds[4];
    __shared__ float s_lz;
    const int t = threadIdx.x, wv = t >> 6, ln = t & 63;
    const unsigned short* l = lg + (size_t)blockIdx.x * OUT_N;
    float* o = out + (size_t)blockIdx.x * OUT_N;

    float m = -3.4e38f, s = 0.f;
    for (int i = t; i < 1250; i += 256) {
        uint4 v = ((const uint4*)l)[i];
        rowbuf[i] = v;
        unsigned w[4] = {v.x, v.y, v.z, v.w};
        float f[8];
        #pragma unroll
        for (int j = 0; j < 4; ++j) {
            f[2*j]   = __builtin_bit_cast(float, w[j] << 16);
            f[2*j+1] = __builtin_bit_cast(float, w[j] & 0xffff0000u);
        }
        float cm = fmaxf(fmaxf(fmaxf(f[0], f[1]), fmaxf(f[2], f[3])),
                         fmaxf(fmaxf(f[4], f[5]), fmaxf(f[6], f[7])));
        if (cm > m) { s *= __expf(m - cm); m = cm; }
        #pragma unroll
        for (int j = 0; j < 8; ++j) s += __expf(f[j] - m);
    }
    #pragma unroll
    for (int off = 32; off > 0; off >>= 1) {
        float om = __shfl_xor(m, off, 64);
        float os = __shfl_xor(s, off, 64);
        float nm = fmaxf(m, om);
        s = s * __expf(m - nm) + os * __expf(om - nm);
        m = nm;
    }
    if (ln == 0) { redm[wv] = m; reds[wv] = s; }
    __syncthreads();
    if (t == 0) {
        float gm = fmaxf(fmaxf(redm[0], redm[1]), fmaxf(redm[2], redm[3]));
        float gs = reds[0] * __expf(redm[0] - gm) + reds[1] * __expf(redm[1] - gm)
                 + reds[2] * __expf(redm[2] - gm) + reds[3] * __expf(redm[3] - gm);
        s_lz = gm + logf(gs);
    }
    __syncthreads();
    const float lz = s_lz;

    for (int i = t; i < 1250; i += 256) {
        uint4 v = rowbuf[i];
        unsigned w[4] = {v.x, v.y, v.z, v.w};
        float4 o0, o1;
        o0.x = __builtin_bit_cast(float, w[0] << 16)          - lz;
        o0.y = __builtin_bit_cast(float, w[0] & 0xffff0000u)  - lz;
        o0.z = __builtin_bit_cast(float, w[1] << 16)          - lz;
        o0.w = __builtin_bit_cast(float, w[1] & 0xffff0000u)  - lz;
        o1.x = __builtin_bit_cast(float, w[2] << 16)          - lz;
        o1.y = __builtin_bit_cast(float, w[2] & 0xffff0000u)  - lz;
        o1.z = __builtin_bit_cast(float, w[3] << 16)          - lz;
        o1.w = __builtin_bit_cast(float, w[3] & 0xffff0000u)  - lz;
        ((float4*)o)[2 * i]     = o0;
        ((float4*)o)[2 * i + 1] = o1;
    }
}

// --------------------------------------------- logsoftmax, fp32 in-place ---
__global__ __launch_bounds__(256) void lsm_f(float* __restrict__ out) {
    __shared__ __align__(16) float rowbuf[OUT_N];
    __shared__ float red[8];
    const int t = threadIdx.x, wv = t >> 6, ln = t & 63;
    float* o = out + (size_t)blockIdx.x * OUT_N;

    float mx = -3.4e38f;
    for (int i = t; i < OUT_N / 4; i += 256) {
        float4 v = ((const float4*)o)[i];
        rowbuf[i*4] = v.x; rowbuf[i*4+1] = v.y; rowbuf[i*4+2] = v.z; rowbuf[i*4+3] = v.w;
        mx = fmaxf(fmaxf(mx, fmaxf(v.x, v.y)), fmaxf(v.z, v.w));
    }
    #pragma unroll
    for (int off = 32; off > 0; off >>= 1) mx = fmaxf(mx, __shfl_xor(mx, off, 64));
    if (ln == 0) red[wv] = mx;
    __syncthreads();
    float m4 = fmaxf(fmaxf(red[0], red[1]), fmaxf(red[2], red[3]));

    float s = 0.f;
    for (int i = t; i < OUT_N; i += 256) s += __expf(rowbuf[i] - m4);
    #pragma unroll
    for (int off = 32; off > 0; off >>= 1) s += __shfl_xor(s, off, 64);
    if (ln == 0) red[4 + wv] = s;
    __syncthreads();
    float lz = m4 + logf(red[4] + red[5] + red[6] + red[7]);

    for (int i = t; i < OUT_N / 4; i += 256) {
        float4 v = { rowbuf[i*4] - lz, rowbuf[i*4+1] - lz,
                     rowbuf[i*4+2] - lz, rowbuf[i*4+3] - lz };
        ((float4*)o)[i] = v;
    }
}

// ----------------------------------------------------------------- launch ---
extern "C" void kernel_launch(void* const* d_in, const int* in_sizes, int n_in,
                              void* d_out, int out_size, void* d_ws, size_t ws_size,
                              hipStream_t stream) {
    const float* d_onehot    = (const float*)d_in[0];
    const int*   cat_ix      = (const int*)  d_in[1];
    const int*   hvb_ix      = (const int*)  d_in[2];
    const int*   hvf_ix      = (const int*)  d_in[3];
    const float* hvb_top     = (const float*)d_in[4];
    const float* hvf_top     = (const float*)d_in[5];
    const float* cat_embeds  = (const float*)d_in[6];
    const float* hvec_embeds = (const float*)d_in[7];
    const float* W1          = (const float*)d_in[8];
    const float* b1          = (const float*)d_in[9];
    const float* W2          = (const float*)d_in[10];
    const float* b2          = (const float*)d_in[11];
    float* out = (float*)d_out;

    unsigned short* xb  = (unsigned short*)d_ws;               // 2048 x 704
    unsigned short* W1b = xb  + (size_t)B_ * K1;               // 1024 x 704
    unsigned short* hB  = W1b + (size_t)HIDDEN * K1;           // 2048 x 1024
    unsigned short* W2b = hB  + (size_t)B_ * HIDDEN;           // 10000 x 1024
    unsigned short* lg  = W2b + (size_t)OUT_N * HIDDEN;        // 2048 x 10000 bf16 logits
    const size_t need = ((size_t)B_*K1 + (size_t)HIDDEN*K1 + (size_t)B_*HIDDEN
                         + (size_t)OUT_N*HIDDEN + (size_t)B_*OUT_N) * 2;
    const bool bf16_logits = (ws_size >= need);

    prep_light<<<dim3(NB_W1 + B_), dim3(256), 0, stream>>>(
        W1, W1b, d_onehot, cat_ix, hvb_ix, hvf_ix,
        hvb_top, hvf_top, cat_embeds, hvec_embeds, xb);
    // mid: GEMM1 (256 blocks) + cvt_w2 (5000 blocks) in one dispatch
    mid<<<dim3(256 + NB_W2), dim3(256), 0, stream>>>(xb, W1b, b1, hB, W2, W2b);
    if (bf16_logits) {
        gemm2_m<<<dim3(256), dim3(512), 0, stream>>>(hB, W2b, b2, lg);
        lsm_b<<<dim3(B_), dim3(256), 0, stream>>>(lg, out);
    } else {
        gemm_rt<4, 2><<<dim3(16 * 79), dim3(256), 0, stream>>>(
            hB, W2b, b2, (void*)out, HIDDEN, HIDDEN / 32, OUT_N, OUT_N - 1, 16);
        lsm_f<<<dim3(B_), dim3(256), 0, stream>>>(out);
    }
}